// Round 2
// baseline (1331.661 us; speedup 1.0000x reference)
//
#include <hip/hip_runtime.h>
#include <hip/hip_fp16.h>
#include <hip/hip_cooperative_groups.h>

namespace cg = cooperative_groups;

#define BB 4
#define CC 3
#define HH 384
#define WW 384
#define HW (HH * WW)
#define KK 5
#define RR 2
#define K2 25
#define ROWS 3           // rows per workgroup
#define NBLK 512         // (384/3) row-blocks * 4 images
#define NTHR 192         // 3 waves, one wave per row
#define NITER 20
#define PAD 1024         // guard floats around each x buffer (max OOB reach is 770)

static constexpr float INV_Z2 = 1.0f / (0.15f * 0.15f);

// ===========================================================================
// Cooperative kernel: weights live in LDS for all 20 iterations.
// Block = 3 rows x 384 cols of one image. Wave w handles row r0+w,
// lane l handles the 6 columns [6l, 6l+5].
// OOB taps are exact zeros (exp underflow after the +10 shift), so the
// iteration loop reads x branch-free into padded guard zones.
// ===========================================================================
__global__ __launch_bounds__(NTHR, 1) void apro_coop(
    const float* __restrict__ img, const float* __restrict__ feat,
    const float* __restrict__ mask, float* __restrict__ out,
    float* __restrict__ xa, float* __restrict__ xb)
{
    __shared__ __half lw[ROWS][K2][WW];   // 3*25*384*2 = 57.6 KB -> 2 blocks/CU

    cg::grid_group grid = cg::this_grid();

    const int wg   = blockIdx.x;
    const int b    = wg >> 7;              // 128 row-blocks per image
    const int r0   = (wg & 127) * ROWS;
    const int wave = threadIdx.x >> 6;
    const int lane = threadIdx.x & 63;
    const int ri   = r0 + wave;            // my row
    const int c0   = lane * 6;             // my first column
    const int rowoff = ri * WW + c0;
    const size_t bHW = (size_t)b * HW;

    const float* imgb = img + (size_t)b * CC * HW;

    // ---- x0 = feat * mask; keep mask in registers for all iterations ----
    float m[6];
#pragma unroll
    for (int j = 0; j < 6; ++j) {
        m[j] = mask[bHW + rowoff + j];
        xa[bHW + rowoff + j] = feat[bHW + rowoff + j] * m[j];
    }

    // ---- per-pixel 5x5 normalized affinity -> fp16 in LDS ----
    for (int j = 0; j < 6; ++j) {
        const int cx = c0 + j;
        float v0 = imgb[0 * HW + rowoff + j] + 10.f;
        float v1 = imgb[1 * HW + rowoff + j] + 10.f;
        float v2 = imgb[2 * HW + rowoff + j] + 10.f;
        float a[K2];
        float sz = 1e-10f;
#pragma unroll
        for (int t = 0; t < K2; ++t) {
            int dr = t / KK - RR, dc = t % KK - RR;
            int rr = ri + dr, cc2 = cx + dc;
            float av = 0.f;
            if (rr >= 0 && rr < HH && cc2 >= 0 && cc2 < WW) {
                int q = rr * WW + cc2;
                float d0 = imgb[0 * HW + q] + 10.f - v0;
                float d1 = imgb[1 * HW + q] + 10.f - v1;
                float d2 = imgb[2 * HW + q] + 10.f - v2;
                av = __expf(-(d0 * d0 + d1 * d1 + d2 * d2) * INV_Z2);
            }
            a[t] = av;
            sz += av;
        }
        float inv = 1.f / sz;
#pragma unroll
        for (int t = 0; t < K2; ++t)
            lw[wave][t][cx] = __float2half(a[t] * inv);
    }

    grid.sync();

    // ---- 20 propagation iterations, weights from LDS, x via global ping-pong
    for (int it = 0; it < NITER; ++it) {
        const float* cur = (it & 1) ? xb : xa;
        float* nxt = (it & 1) ? xa : xb;

        float acc[6] = {0, 0, 0, 0, 0, 0};
        const float* base = cur + bHW + rowoff - 2;   // col c0-2 of my row
#pragma unroll
        for (int dr = -2; dr <= 2; ++dr) {
            const float* p = base + dr * WW;          // x[ri+dr][c0-2 .. c0+7]
            float xs[10];
#pragma unroll
            for (int q = 0; q < 5; ++q) {             // 8-byte aligned float2 loads
                float2 v = *(const float2*)(p + 2 * q);
                xs[2 * q] = v.x; xs[2 * q + 1] = v.y;
            }
#pragma unroll
            for (int dc = 0; dc < 5; ++dc) {
                const int t = (dr + 2) * 5 + dc;
                const __half2* wp = (const __half2*)&lw[wave][t][c0]; // c0 even -> 4B aligned
                float2 f01 = __half22float2(wp[0]);
                float2 f23 = __half22float2(wp[1]);
                float2 f45 = __half22float2(wp[2]);
                acc[0] = fmaf(f01.x, xs[dc + 0], acc[0]);
                acc[1] = fmaf(f01.y, xs[dc + 1], acc[1]);
                acc[2] = fmaf(f23.x, xs[dc + 2], acc[2]);
                acc[3] = fmaf(f23.y, xs[dc + 3], acc[3]);
                acc[4] = fmaf(f45.x, xs[dc + 4], acc[4]);
                acc[5] = fmaf(f45.y, xs[dc + 5], acc[5]);
            }
        }
        if (it == NITER - 1) {
#pragma unroll
            for (int j = 0; j < 6; ++j)
                out[bHW + rowoff + j] = acc[j] * m[j];
        } else {
#pragma unroll
            for (int j = 0; j < 6; ++j)
                nxt[bHW + rowoff + j] = acc[j] * m[j];
            grid.sync();
        }
    }
}

// ===========================================================================
// Fallback path (round-1 kernels) in case cooperative launch is rejected.
// ===========================================================================
__global__ __launch_bounds__(256) void prep_kernel(
    const float* __restrict__ img, const float* __restrict__ feat,
    const float* __restrict__ mask, float* __restrict__ wgt,
    float* __restrict__ x0)
{
    int idx = blockIdx.x * blockDim.x + threadIdx.x;
    if (idx >= BB * HW) return;
    int b = idx / HW;
    int rem = idx - b * HW;
    int h = rem / WW;
    int wc = rem - h * WW;

    const float* imgb = img + (size_t)b * CC * HW;
    float c0 = imgb[0 * HW + rem] + 10.0f;
    float c1 = imgb[1 * HW + rem] + 10.0f;
    float c2 = imgb[2 * HW + rem] + 10.0f;

    float aff[K2];
    float sumz = 1e-10f;
#pragma unroll
    for (int t = 0; t < K2; ++t) {
        int di = t / KK - RR, dj = t % KK - RR;
        int hh = h + di, ww = wc + dj;
        float a = 0.0f;
        if (hh >= 0 && hh < HH && ww >= 0 && ww < WW) {
            int q = hh * WW + ww;
            float d0 = imgb[0 * HW + q] + 10.0f - c0;
            float d1 = imgb[1 * HW + q] + 10.0f - c1;
            float d2 = imgb[2 * HW + q] + 10.0f - c2;
            a = __expf(-(d0 * d0 + d1 * d1 + d2 * d2) * INV_Z2);
        }
        aff[t] = a;
        sumz += a;
    }
    float inv = 1.0f / sumz;
#pragma unroll
    for (int t = 0; t < K2; ++t)
        wgt[((size_t)b * K2 + t) * HW + rem] = aff[t] * inv;

    x0[idx] = feat[idx] * mask[idx];
}

__global__ __launch_bounds__(256) void iter_kernel(
    const float* __restrict__ wgt, const float* __restrict__ xin,
    const float* __restrict__ mask, float* __restrict__ xout)
{
    int idx = blockIdx.x * blockDim.x + threadIdx.x;
    if (idx >= BB * HW) return;
    int b = idx / HW;
    int rem = idx - b * HW;
    int h = rem / WW;
    int wc = rem - h * WW;

    const float* wb = wgt + (size_t)b * K2 * HW + rem;
    const float* xb = xin + (size_t)b * HW;

    float acc = 0.0f;
    if (h >= RR && h < HH - RR && wc >= RR && wc < WW - RR) {
#pragma unroll
        for (int t = 0; t < K2; ++t) {
            int di = t / KK - RR, dj = t % KK - RR;
            acc += wb[(size_t)t * HW] * xb[rem + di * WW + dj];
        }
    } else {
#pragma unroll
        for (int t = 0; t < K2; ++t) {
            int di = t / KK - RR, dj = t % KK - RR;
            int hh = h + di, ww = wc + dj;
            if (hh >= 0 && hh < HH && ww >= 0 && ww < WW)
                acc += wb[(size_t)t * HW] * xb[hh * WW + ww];
        }
    }
    xout[idx] = acc * mask[idx];
}

extern "C" void kernel_launch(void* const* d_in, const int* in_sizes, int n_in,
                              void* d_out, int out_size, void* d_ws, size_t ws_size,
                              hipStream_t stream)
{
    const float* img  = (const float*)d_in[0];
    const float* feat = (const float*)d_in[1];
    const float* mask = (const float*)d_in[2];
    float* out = (float*)d_out;

    // coop layout: [PAD | xa | PAD | xb | PAD] floats
    float* base = (float*)d_ws;
    float* xa = base + PAD;
    float* xb = xa + (size_t)BB * HW + PAD;

    void* args[6] = {(void*)&img, (void*)&feat, (void*)&mask,
                     (void*)&out, (void*)&xa, (void*)&xb};
    hipError_t e = hipLaunchCooperativeKernel((const void*)apro_coop,
                                              dim3(NBLK), dim3(NTHR),
                                              args, 0, stream);
    if (e == hipSuccess) return;

    // ---- fallback: non-cooperative multi-kernel path ----
    float* wgt = (float*)d_ws;                    // B*25*HW fp32
    float* fxa = wgt + (size_t)BB * K2 * HW;
    float* fxb = fxa + (size_t)BB * HW;

    const int n = BB * HW;
    const int blocks = (n + 255) / 256;
    prep_kernel<<<blocks, 256, 0, stream>>>(img, feat, mask, wgt, fxa);
    float* cur = fxa;
    float* nxt = fxb;
    for (int it = 0; it < NITER - 1; ++it) {
        iter_kernel<<<blocks, 256, 0, stream>>>(wgt, cur, mask, nxt);
        float* t = cur; cur = nxt; nxt = t;
    }
    iter_kernel<<<blocks, 256, 0, stream>>>(wgt, cur, mask, out);
}

// Round 3
// 234.761 us; speedup vs baseline: 5.6724x; 5.6724x over previous
//
#include <hip/hip_runtime.h>
#include <hip/hip_fp16.h>

#define BB 4
#define CC 3
#define HH 384
#define WW 384
#define HW (HH * WW)
#define KK 5
#define RR 2
#define K2 25
#define NITER 20
#define PADF 2048   // guard floats around each x buffer (max OOB reach is 772)

static constexpr float INV_Z2 = 1.0f / (0.15f * 0.15f);

// ---------------------------------------------------------------------------
// prep: 2 px/thread. Per-pixel 5x5 normalized affinity -> fp16 planes
// wgt[b][t][pix], plus x0 = feat*mask. OOB taps are exactly 0 (the +10 shift
// makes the exponent ~-1.3e4 -> fp32 exp underflows to +0), so iter kernels
// can read x branch-free through padded guards.
// ---------------------------------------------------------------------------
__global__ __launch_bounds__(256) void prep2(
    const float* __restrict__ img, const float* __restrict__ feat,
    const float* __restrict__ mask, __half* __restrict__ wgt,
    float* __restrict__ x0)
{
    int gid = blockIdx.x * 256 + threadIdx.x;
    int p0 = gid * 2;
    if (p0 >= BB * HW) return;
    int b   = p0 / HW;
    int rem = p0 - b * HW;          // even
    int h   = rem / WW;
    int wc  = rem - h * WW;

    const float* imgb = img + (size_t)b * CC * HW;
    const size_t bHW = (size_t)b * HW;

    float2 f  = *(const float2*)(feat + bHW + rem);
    float2 mk = *(const float2*)(mask + bHW + rem);
    *(float2*)(x0 + bHW + rem) = make_float2(f.x * mk.x, f.y * mk.y);

    float v0[2], v1[2], v2[2];
#pragma unroll
    for (int s = 0; s < 2; ++s) {
        v0[s] = imgb[0 * HW + rem + s] + 10.f;
        v1[s] = imgb[1 * HW + rem + s] + 10.f;
        v2[s] = imgb[2 * HW + rem + s] + 10.f;
    }

    float a[2][K2];
    float sz[2] = {1e-10f, 1e-10f};
#pragma unroll
    for (int t = 0; t < K2; ++t) {
        int dr = t / KK - RR, dc = t % KK - RR;
        int rr = h + dr;
#pragma unroll
        for (int s = 0; s < 2; ++s) {
            int cc2 = wc + s + dc;
            float av = 0.f;
            if (rr >= 0 && rr < HH && cc2 >= 0 && cc2 < WW) {
                int q = rr * WW + cc2;
                float d0 = imgb[0 * HW + q] + 10.f - v0[s];
                float d1 = imgb[1 * HW + q] + 10.f - v1[s];
                float d2 = imgb[2 * HW + q] + 10.f - v2[s];
                av = __expf(-(d0 * d0 + d1 * d1 + d2 * d2) * INV_Z2);
            }
            a[s][t] = av;
            sz[s] += av;
        }
    }
    float i0 = 1.f / sz[0], i1 = 1.f / sz[1];
#pragma unroll
    for (int t = 0; t < K2; ++t) {
        __half2 hv = __floats2half2_rn(a[0][t] * i0, a[1][t] * i1);
        *(__half2*)(wgt + ((size_t)b * K2 + t) * HW + rem) = hv;
    }
}

// ---------------------------------------------------------------------------
// One iteration, 8 px/thread, all loads 16B. Branch-free: OOB x reads land in
// guard pads / neighboring rows and are multiplied by exactly-zero weights.
// ---------------------------------------------------------------------------
__global__ __launch_bounds__(256) void iter8(
    const __half* __restrict__ wgt, const float* __restrict__ xin,
    const float* __restrict__ mask, float* __restrict__ xout)
{
    int gid = blockIdx.x * 256 + threadIdx.x;
    int p0 = gid * 8;                      // grid sized exactly: p0 < BB*HW
    int b   = p0 / HW;
    int rem = p0 - b * HW;                 // multiple of 8
    const size_t bHW = (size_t)b * HW;

    const float*  xb = xin + bHW;
    const __half* wb = wgt + (size_t)b * K2 * HW + rem;

    float acc[8] = {0, 0, 0, 0, 0, 0, 0, 0};
#pragma unroll
    for (int dr = -2; dr <= 2; ++dr) {
        // x row h+dr, cols c0-4 .. c0+11, four aligned float4 loads
        const float* p = xb + rem + dr * WW - 4;
        float xs[16];
#pragma unroll
        for (int q = 0; q < 4; ++q) {
            float4 v = *(const float4*)(p + 4 * q);
            xs[4 * q + 0] = v.x; xs[4 * q + 1] = v.y;
            xs[4 * q + 2] = v.z; xs[4 * q + 3] = v.w;
        }
#pragma unroll
        for (int dc = 0; dc < 5; ++dc) {
            const int t = (dr + 2) * 5 + dc;
            float4 wv4 = *(const float4*)(wb + (size_t)t * HW);  // 8 halves
            const __half2* hp = (const __half2*)&wv4;
            float2 w01 = __half22float2(hp[0]);
            float2 w23 = __half22float2(hp[1]);
            float2 w45 = __half22float2(hp[2]);
            float2 w67 = __half22float2(hp[3]);
            acc[0] = fmaf(w01.x, xs[dc + 2], acc[0]);
            acc[1] = fmaf(w01.y, xs[dc + 3], acc[1]);
            acc[2] = fmaf(w23.x, xs[dc + 4], acc[2]);
            acc[3] = fmaf(w23.y, xs[dc + 5], acc[3]);
            acc[4] = fmaf(w45.x, xs[dc + 6], acc[4]);
            acc[5] = fmaf(w45.y, xs[dc + 7], acc[5]);
            acc[6] = fmaf(w67.x, xs[dc + 8], acc[6]);
            acc[7] = fmaf(w67.y, xs[dc + 9], acc[7]);
        }
    }
    float4 m0 = *(const float4*)(mask + bHW + rem);
    float4 m1 = *(const float4*)(mask + bHW + rem + 4);
    float4 o0 = make_float4(acc[0] * m0.x, acc[1] * m0.y,
                            acc[2] * m0.z, acc[3] * m0.w);
    float4 o1 = make_float4(acc[4] * m1.x, acc[5] * m1.y,
                            acc[6] * m1.z, acc[7] * m1.w);
    *(float4*)(xout + bHW + rem)     = o0;
    *(float4*)(xout + bHW + rem + 4) = o1;
}

extern "C" void kernel_launch(void* const* d_in, const int* in_sizes, int n_in,
                              void* d_out, int out_size, void* d_ws, size_t ws_size,
                              hipStream_t stream)
{
    const float* img  = (const float*)d_in[0];
    const float* feat = (const float*)d_in[1];
    const float* mask = (const float*)d_in[2];
    float* out = (float*)d_out;

    // ws layout: [ wgt: B*25*HW halves (~29.5 MB) | PADF | xa | PADF | xb | PADF ]
    __half* wgt = (__half*)d_ws;
    float* fbase = (float*)((char*)d_ws + ((size_t)BB * K2 * HW * sizeof(__half) + 255 & ~(size_t)255));
    float* xa = fbase + PADF;
    float* xb = xa + (size_t)BB * HW + PADF;

    const int n = BB * HW;
    prep2<<<(n / 2 + 255) / 256, 256, 0, stream>>>(img, feat, mask, wgt, xa);

    const int iblocks = n / 8 / 256;   // 288, exact
    float* cur = xa;
    float* nxt = xb;
    for (int it = 0; it < NITER - 1; ++it) {
        iter8<<<iblocks, 256, 0, stream>>>(wgt, cur, mask, nxt);
        float* t = cur; cur = nxt; nxt = t;
    }
    iter8<<<iblocks, 256, 0, stream>>>(wgt, cur, mask, out);
}